// Round 2
// baseline (3732.485 us; speedup 1.0000x reference)
//
#include <hip/hip_runtime.h>

#define M_DIM 4096
#define K_DIM 4096
#define N_DIM 32768
#define TOPK  64
#define NCAND 96
#define NT    (K_DIM / 64)   // 64 K-tiles of BK=64

typedef __attribute__((ext_vector_type(8))) _Float16 half8;
typedef __attribute__((ext_vector_type(4))) _Float16 half4;
typedef __attribute__((ext_vector_type(4))) float    f32x4;

#define GLDS(gp, lp) __builtin_amdgcn_global_load_lds( \
    (const __attribute__((address_space(1))) void*)(gp), \
    (__attribute__((address_space(3))) void*)(lp), 16, 0, 0)

// raw barrier / counted waits with compiler memory fences (no vmcnt drain at barriers)
#define BARX()  asm volatile("s_barrier" ::: "memory")
#define LGKM0() asm volatile("s_waitcnt lgkmcnt(0)" ::: "memory")
#define VMC6()  asm volatile("s_waitcnt vmcnt(6)" ::: "memory")
#define VMC0()  asm volatile("s_waitcnt vmcnt(0)" ::: "memory")

// ---------------- cast: fp32 -> fp16 (hi only; refine restores precision) -------
__launch_bounds__(256)
__global__ void cast_kernel(const float4* __restrict__ src, half4* __restrict__ dst, int n4) {
  int i = blockIdx.x * blockDim.x + threadIdx.x;
  int stride = gridDim.x * blockDim.x;
  for (; i < n4; i += stride) {
    float4 x = src[i];
    half4 h;
    h[0] = (_Float16)x.x; h[1] = (_Float16)x.y; h[2] = (_Float16)x.z; h[3] = (_Float16)x.w;
    dst[i] = h;
  }
}

// ---------------- encode GEMM: 256x256 tile, BK=64, 8-phase counted-vmcnt -------
// (frozen this round: control group. 1140 us, MfmaUtil 43%)
__launch_bounds__(512, 2)
__global__ void gemm_enc(const _Float16* __restrict__ xh, const _Float16* __restrict__ wh,
                         const float* __restrict__ b_enc, float* __restrict__ a1)
{
  __shared__ alignas(16) _Float16 lds[2 * 4 * 8192];   // 128 KiB

  const int tid  = threadIdx.x;
  const int lane = tid & 63;
  const int wave = tid >> 6;
  const int wm = wave >> 2;      // 0..1 (M half)
  const int wn = wave & 3;       // 0..3 (N quarter)

  const int bid  = blockIdx.x;
  const int xcd  = bid & 7;
  const int bi   = bid >> 3;           // 0..255
  const int ncol = xcd * 16 + (bi >> 4);
  const int mrow = bi & 15;
  const int m0 = mrow << 8;
  const int n0 = ncol << 8;

  const int srow   = tid >> 3;
  const int schunk = (tid & 7) ^ (srow & 7);
  const _Float16* pA = xh + (size_t)(m0 + srow) * K_DIM + schunk * 8;
  const _Float16* pB = wh + (size_t)(n0 + srow) * K_DIM + schunk * 8;
  const int sdst = tid * 8;

  const int l15 = lane & 15, l7 = lane & 7, kq = lane >> 4;
  const int c0  = kq ^ l7;
  const int ck0 = c0 * 8, ck1 = (c0 ^ 4) * 8;
  const int arow = l15 * 64;
  const int brow = (wn & 1) * 4096 + l15 * 64;

  f32x4 acc[8][4];
  const f32x4 zero = {0.f, 0.f, 0.f, 0.f};
#pragma unroll
  for (int im = 0; im < 8; ++im)
#pragma unroll
    for (int jn = 0; jn < 4; ++jn) acc[im][jn] = zero;

#define STAGE(c, t) do { \
    const _Float16* sp_ = (((c) >= 2) ? pA : pB) + (size_t)((c) & 1) * 128 * K_DIM + (t) * 64; \
    _Float16* dp_ = &lds[(((((t) & 1) << 2) | (c)) << 13) + sdst]; \
    GLDS(sp_, dp_); \
    GLDS(sp_ + 64 * K_DIM, dp_ + 4096); \
  } while (0)

  half8 a_[4][2], b_[4][2];

#define LDA(mh, ab) do { \
    _Pragma("unroll") for (int mt = 0; mt < 4; ++mt) { \
      a_[mt][0] = *(const half8*)&lds[(ab) + (mh) * 4096 + mt * 1024 + arow + ck0]; \
      a_[mt][1] = *(const half8*)&lds[(ab) + (mh) * 4096 + mt * 1024 + arow + ck1]; \
    } } while (0)

#define LDB(bb) do { \
    _Pragma("unroll") for (int nt = 0; nt < 4; ++nt) { \
      b_[nt][0] = *(const half8*)&lds[(bb) + nt * 1024 + brow + ck0]; \
      b_[nt][1] = *(const half8*)&lds[(bb) + nt * 1024 + brow + ck1]; \
    } } while (0)

#define QUAD(mh, nh) do { \
    _Pragma("unroll") for (int mt = 0; mt < 4; ++mt) \
    _Pragma("unroll") for (int nt = 0; nt < 2; ++nt) { \
      acc[(mh)*4+mt][(nh)*2+nt] = __builtin_amdgcn_mfma_f32_16x16x32_f16( \
          a_[mt][0], b_[(nh)*2+nt][0], acc[(mh)*4+mt][(nh)*2+nt], 0, 0, 0); \
      acc[(mh)*4+mt][(nh)*2+nt] = __builtin_amdgcn_mfma_f32_16x16x32_f16( \
          a_[mt][1], b_[(nh)*2+nt][1], acc[(mh)*4+mt][(nh)*2+nt], 0, 0, 0); \
    } } while (0)

  STAGE(0, 0); STAGE(1, 0); STAGE(2, 0); STAGE(3, 0);
  STAGE(0, 1); STAGE(1, 1); STAGE(2, 1);
  VMC6();
  BARX();

  for (int T = 0; T < NT; ++T) {
    const int ab = (((T & 1) << 2) + 2 + wm) << 13;
    const int bb = (((T & 1) << 2) + (wn >> 1)) << 13;
    // phase 1
    LDA(0, ab);
    LDB(bb);
    if (T + 1 < NT) STAGE(3, T + 1);
    BARX(); LGKM0();
    __builtin_amdgcn_s_setprio(1); QUAD(0, 0); __builtin_amdgcn_s_setprio(0);
    BARX();
    // phase 2
    if (T + 2 < NT) STAGE(0, T + 2);
    BARX();
    __builtin_amdgcn_s_setprio(1); QUAD(0, 1); __builtin_amdgcn_s_setprio(0);
    BARX();
    // phase 3
    LDA(1, ab);
    if (T + 2 < NT) STAGE(1, T + 2);
    BARX(); LGKM0();
    __builtin_amdgcn_s_setprio(1); QUAD(1, 0); __builtin_amdgcn_s_setprio(0);
    BARX();
    // phase 4
    if (T + 2 < NT) STAGE(2, T + 2);
    BARX();
    __builtin_amdgcn_s_setprio(1); QUAD(1, 1); __builtin_amdgcn_s_setprio(0);
    if (T < NT - 2) { VMC6(); } else { VMC0(); }
    BARX();
  }

  const int col = lane & 15;
  const int r4  = (lane >> 4) << 2;
#pragma unroll
  for (int nt = 0; nt < 4; ++nt) {
    const int gc = n0 + wn * 64 + nt * 16 + col;
    const float bias = b_enc[gc];
#pragma unroll
    for (int mt = 0; mt < 8; ++mt) {
#pragma unroll
      for (int r = 0; r < 4; ++r) {
        const int gr = m0 + wm * 128 + mt * 16 + r4 + r;
        a1[(size_t)gr * N_DIM + gc] = acc[mt][nt][r] + bias;
      }
    }
  }
#undef STAGE
#undef LDA
#undef LDB
#undef QUAD
}

// ---------------- top-96 per row on fp16-approx acts: bitwise radix select -------
#define TK_THREADS 512
#define TK_PER 64   // 32768 / 512
__launch_bounds__(512)
__global__ void topk_kernel(const float* __restrict__ a1, int* __restrict__ cand)
{
  const int row = blockIdx.x;
  const float* pr = a1 + (size_t)row * N_DIM;
  const int tid = threadIdx.x;

  unsigned u[TK_PER];
#pragma unroll
  for (int i = 0; i < TK_PER; ++i) {
    union { float f; unsigned b; } c;
    c.f = pr[i * TK_THREADS + tid];
    u[i] = (c.b & 0x80000000u) ? ~c.b : (c.b | 0x80000000u);  // order-preserving key
  }

  __shared__ int red[8];
  unsigned prefix = 0;
  int needed = NCAND;
  for (int bit = 31; bit >= 0; --bit) {
    unsigned want = (prefix >> bit) | 1u;
    int cnt = 0;
#pragma unroll
    for (int i = 0; i < TK_PER; ++i) cnt += ((u[i] >> bit) == want) ? 1 : 0;
    for (int off = 32; off > 0; off >>= 1) cnt += __shfl_down(cnt, off);
    if ((tid & 63) == 0) red[tid >> 6] = cnt;
    __syncthreads();
    int total = red[0] + red[1] + red[2] + red[3] + red[4] + red[5] + red[6] + red[7];
    __syncthreads();
    if (total >= needed) prefix |= (1u << bit);
    else needed -= total;
  }
  __shared__ int c_gt, c_tie;
  if (tid == 0) { c_gt = 0; c_tie = 0; }
  __syncthreads();
#pragma unroll
  for (int i = 0; i < TK_PER; ++i) {
    if (u[i] > prefix) {
      int p = atomicAdd(&c_gt, 1);
      cand[row * NCAND + p] = i * TK_THREADS + tid;
    }
  }
  __syncthreads();
  int base = c_gt;
#pragma unroll
  for (int i = 0; i < TK_PER; ++i) {
    if (u[i] == prefix) {
      int t = atomicAdd(&c_tie, 1);
      if (t < needed) cand[row * NCAND + base + t] = i * TK_THREADS + tid;
    }
  }
}

// ---------------- inverted refine: W single-pass, x gathered from L3 ------------
__launch_bounds__(256)
__global__ void clear_kernel(int* __restrict__ counts) {
  int i = blockIdx.x * 256 + threadIdx.x;
  if (i < N_DIM) counts[i] = 0;
}

__launch_bounds__(256)
__global__ void scatter_kernel(const int* __restrict__ cand, int* __restrict__ counts,
                               int* __restrict__ entries) {
  int i = blockIdx.x * 256 + threadIdx.x;   // 0 .. 4096*96-1
  int cj = cand[i];
  int row = i / NCAND;
  int j = i - row * NCAND;
  int pos = atomicAdd(&counts[cj], 1);
  if (pos < NCAND) entries[cj * NCAND + pos] = (row << 7) | j;
}

// one block per W-row: stage row in LDS, 4 waves round-robin the referencing x-rows.
// per-lane accumulation + shfl tree textually identical to the previous (passing)
// refine_kernel -> bitwise-identical vals -> identical selection.
__launch_bounds__(256)
__global__ void rvals_kernel(const float* __restrict__ x, const float* __restrict__ W,
                             const float* __restrict__ b_enc,
                             const int* __restrict__ counts, const int* __restrict__ entries,
                             float* __restrict__ vals)
{
  const int n = blockIdx.x;
  int c = counts[n];
  if (c == 0) return;
  if (c > NCAND) c = NCAND;
  __shared__ float sw[K_DIM];
  const int tid = threadIdx.x, lane = tid & 63, wave = tid >> 6;
  const float* wr = W + (size_t)n * K_DIM;
#pragma unroll
  for (int t = 0; t < 4; ++t)
    *(float4*)&sw[t * 1024 + tid * 4] = *(const float4*)&wr[t * 1024 + tid * 4];
  __syncthreads();
  const float bias = b_enc[n];
  for (int e = wave; e < c; e += 4) {
    const int pk  = entries[n * NCAND + e];
    const int row = pk >> 7, j = pk & 127;
    const float* xr = x + (size_t)row * K_DIM;
    float acc = 0.f;
#pragma unroll
    for (int cc = 0; cc < 16; ++cc) {
      float4 xv = *(const float4*)&xr[cc * 256 + lane * 4];
      float4 wv = *(const float4*)&sw[cc * 256 + lane * 4];
      acc += xv.x * wv.x + xv.y * wv.y + xv.z * wv.z + xv.w * wv.w;
    }
#pragma unroll
    for (int off = 32; off > 0; off >>= 1) acc += __shfl_down(acc, off, 64);
    if (lane == 0) vals[row * NCAND + j] = acc + bias;
  }
}

// per-row exact top-64 among the 96 exact vals (same tie-break as before)
__launch_bounds__(128)
__global__ void select_kernel(const int* __restrict__ cand, const float* __restrict__ vals,
                              int* __restrict__ tk_idx, float* __restrict__ tk_val)
{
  const int row = blockIdx.x, tid = threadIdx.x;
  __shared__ float svals[NCAND];
  __shared__ int   sidx[NCAND];
  __shared__ int   spos;
  if (tid == 0) spos = 0;
  if (tid < NCAND) { svals[tid] = vals[row * NCAND + tid]; sidx[tid] = cand[row * NCAND + tid]; }
  __syncthreads();

  if (tid < NCAND) {
    float v = svals[tid];
    int myidx = sidx[tid];
    int rank = 0;
    for (int i = 0; i < NCAND; ++i) {
      float vi = svals[i];
      rank += (vi > v || (vi == v && sidx[i] < myidx)) ? 1 : 0;  // lax.top_k tie-break
    }
    if (rank < TOPK) {
      int p = atomicAdd(&spos, 1);
      tk_idx[row * TOPK + p] = myidx;
      tk_val[row * TOPK + p] = v;
    }
  }
}

// ---------------- sparse tied-weight decode: z2 = sum val_j * W[idx_j,:] + b_dec --
__launch_bounds__(256)
__global__ void decode_kernel(const _Float16* __restrict__ wh, const int* __restrict__ tk_idx,
                              const float* __restrict__ tk_val, const float* __restrict__ b_dec,
                              float* __restrict__ out)
{
  const int row = blockIdx.x, tid = threadIdx.x;
  __shared__ int   sidx[TOPK];
  __shared__ float sval[TOPK];
  if (tid < TOPK) { sidx[tid] = tk_idx[row * TOPK + tid]; sval[tid] = tk_val[row * TOPK + tid]; }
  __syncthreads();

  const int c0 = tid * 8;
  const int c1 = (tid + 256) * 8;
  float acc0[8], acc1[8];
#pragma unroll
  for (int e = 0; e < 8; ++e) { acc0[e] = b_dec[c0 + e]; acc1[e] = b_dec[c1 + e]; }

  for (int j = 0; j < TOPK; ++j) {
    const _Float16* wr = wh + (size_t)sidx[j] * K_DIM;
    half8 w0 = *(const half8*)(wr + c0);
    half8 w1 = *(const half8*)(wr + c1);
    float v = sval[j];
#pragma unroll
    for (int e = 0; e < 8; ++e) { acc0[e] += v * (float)w0[e]; acc1[e] += v * (float)w1[e]; }
  }
  float* po = out + (size_t)row * K_DIM;
#pragma unroll
  for (int e = 0; e < 8; ++e) { po[c0 + e] = acc0[e]; po[c1 + e] = acc1[e]; }
}

extern "C" void kernel_launch(void* const* d_in, const int* in_sizes, int n_in,
                              void* d_out, int out_size, void* d_ws, size_t ws_size,
                              hipStream_t stream) {
  const float* x     = (const float*)d_in[0];
  const float* W     = (const float*)d_in[1];
  const float* b_enc = (const float*)d_in[2];
  const float* b_dec = (const float*)d_in[3];

  // workspace carve (~805 MB)
  _Float16* x_h = (_Float16*)d_ws;
  _Float16* w_h = x_h + (size_t)M_DIM * K_DIM;
  float*    a1  = (float*)(w_h + (size_t)N_DIM * K_DIM);
  int*      cand = (int*)(a1 + (size_t)M_DIM * N_DIM);
  int*      tk_idx = cand + (size_t)M_DIM * NCAND;
  float*    tk_val = (float*)(tk_idx + M_DIM * TOPK);

  // refine scratch aliases a1 (a1 is dead after topk_kernel)
  int*   counts  = (int*)a1;
  int*   entries = counts + N_DIM;
  float* vals    = (float*)(entries + (size_t)N_DIM * NCAND);

  cast_kernel<<<4096, 256, 0, stream>>>((const float4*)x, (half4*)x_h,
                                        (int)((size_t)M_DIM * K_DIM / 4));
  cast_kernel<<<8192, 256, 0, stream>>>((const float4*)W, (half4*)w_h,
                                        (int)((size_t)N_DIM * K_DIM / 4));
  gemm_enc<<<(M_DIM / 256) * (N_DIM / 256), 512, 0, stream>>>(x_h, w_h, b_enc, a1);
  topk_kernel<<<M_DIM, TK_THREADS, 0, stream>>>(a1, cand);
  clear_kernel<<<N_DIM / 256, 256, 0, stream>>>(counts);
  scatter_kernel<<<(M_DIM * NCAND) / 256, 256, 0, stream>>>(cand, counts, entries);
  rvals_kernel<<<N_DIM, 256, 0, stream>>>(x, W, b_enc, counts, entries, vals);
  select_kernel<<<M_DIM, 128, 0, stream>>>(cand, vals, tk_idx, tk_val);
  decode_kernel<<<M_DIM, 256, 0, stream>>>(w_h, tk_idx, tk_val, b_dec, (float*)d_out);
}

// Round 3
// 2996.597 us; speedup vs baseline: 1.2456x; 1.2456x over previous
//
#include <hip/hip_runtime.h>

#define M_DIM 4096
#define K_DIM 4096
#define N_DIM 32768
#define TOPK  64
#define NCAND 96
#define NT    (K_DIM / 64)   // 64 K-tiles of BK=64

typedef __attribute__((ext_vector_type(8))) _Float16 half8;
typedef __attribute__((ext_vector_type(4))) _Float16 half4;
typedef __attribute__((ext_vector_type(4))) float    f32x4;

#define GLDS(gp, lp) __builtin_amdgcn_global_load_lds( \
    (const __attribute__((address_space(1))) void*)(gp), \
    (__attribute__((address_space(3))) void*)(lp), 16, 0, 0)

// raw barrier / counted waits with compiler memory fences (no vmcnt drain at barriers)
#define BARX()  asm volatile("s_barrier" ::: "memory")
#define LGKM0() asm volatile("s_waitcnt lgkmcnt(0)" ::: "memory")
#define VMC6()  asm volatile("s_waitcnt vmcnt(6)" ::: "memory")
#define VMC0()  asm volatile("s_waitcnt vmcnt(0)" ::: "memory")

// certainty margin: 2*delta, delta = 0.02 (~50 sigma of the fp16-GEMM value error)
#define MARGIN2 0.04f

// ---------------- cast: fp32 -> fp16 ------------------------------------------
__launch_bounds__(256)
__global__ void cast_kernel(const float4* __restrict__ src, half4* __restrict__ dst, int n4) {
  int i = blockIdx.x * blockDim.x + threadIdx.x;
  int stride = gridDim.x * blockDim.x;
  for (; i < n4; i += stride) {
    float4 x = src[i];
    half4 h;
    h[0] = (_Float16)x.x; h[1] = (_Float16)x.y; h[2] = (_Float16)x.z; h[3] = (_Float16)x.w;
    dst[i] = h;
  }
}

// ---------------- encode GEMM: 256x256 tile, BK=64, 8-phase counted-vmcnt -------
// (frozen: control group. ~1155 us, MfmaUtil ~43%)
__launch_bounds__(512, 2)
__global__ void gemm_enc(const _Float16* __restrict__ xh, const _Float16* __restrict__ wh,
                         const float* __restrict__ b_enc, float* __restrict__ a1)
{
  __shared__ alignas(16) _Float16 lds[2 * 4 * 8192];   // 128 KiB

  const int tid  = threadIdx.x;
  const int lane = tid & 63;
  const int wave = tid >> 6;
  const int wm = wave >> 2;      // 0..1 (M half)
  const int wn = wave & 3;       // 0..3 (N quarter)

  const int bid  = blockIdx.x;
  const int xcd  = bid & 7;
  const int bi   = bid >> 3;           // 0..255
  const int ncol = xcd * 16 + (bi >> 4);
  const int mrow = bi & 15;
  const int m0 = mrow << 8;
  const int n0 = ncol << 8;

  const int srow   = tid >> 3;
  const int schunk = (tid & 7) ^ (srow & 7);
  const _Float16* pA = xh + (size_t)(m0 + srow) * K_DIM + schunk * 8;
  const _Float16* pB = wh + (size_t)(n0 + srow) * K_DIM + schunk * 8;
  const int sdst = tid * 8;

  const int l15 = lane & 15, l7 = lane & 7, kq = lane >> 4;
  const int c0  = kq ^ l7;
  const int ck0 = c0 * 8, ck1 = (c0 ^ 4) * 8;
  const int arow = l15 * 64;
  const int brow = (wn & 1) * 4096 + l15 * 64;

  f32x4 acc[8][4];
  const f32x4 zero = {0.f, 0.f, 0.f, 0.f};
#pragma unroll
  for (int im = 0; im < 8; ++im)
#pragma unroll
    for (int jn = 0; jn < 4; ++jn) acc[im][jn] = zero;

#define STAGE(c, t) do { \
    const _Float16* sp_ = (((c) >= 2) ? pA : pB) + (size_t)((c) & 1) * 128 * K_DIM + (t) * 64; \
    _Float16* dp_ = &lds[(((((t) & 1) << 2) | (c)) << 13) + sdst]; \
    GLDS(sp_, dp_); \
    GLDS(sp_ + 64 * K_DIM, dp_ + 4096); \
  } while (0)

  half8 a_[4][2], b_[4][2];

#define LDA(mh, ab) do { \
    _Pragma("unroll") for (int mt = 0; mt < 4; ++mt) { \
      a_[mt][0] = *(const half8*)&lds[(ab) + (mh) * 4096 + mt * 1024 + arow + ck0]; \
      a_[mt][1] = *(const half8*)&lds[(ab) + (mh) * 4096 + mt * 1024 + arow + ck1]; \
    } } while (0)

#define LDB(bb) do { \
    _Pragma("unroll") for (int nt = 0; nt < 4; ++nt) { \
      b_[nt][0] = *(const half8*)&lds[(bb) + nt * 1024 + brow + ck0]; \
      b_[nt][1] = *(const half8*)&lds[(bb) + nt * 1024 + brow + ck1]; \
    } } while (0)

#define QUAD(mh, nh) do { \
    _Pragma("unroll") for (int mt = 0; mt < 4; ++mt) \
    _Pragma("unroll") for (int nt = 0; nt < 2; ++nt) { \
      acc[(mh)*4+mt][(nh)*2+nt] = __builtin_amdgcn_mfma_f32_16x16x32_f16( \
          a_[mt][0], b_[(nh)*2+nt][0], acc[(mh)*4+mt][(nh)*2+nt], 0, 0, 0); \
      acc[(mh)*4+mt][(nh)*2+nt] = __builtin_amdgcn_mfma_f32_16x16x32_f16( \
          a_[mt][1], b_[(nh)*2+nt][1], acc[(mh)*4+mt][(nh)*2+nt], 0, 0, 0); \
    } } while (0)

  STAGE(0, 0); STAGE(1, 0); STAGE(2, 0); STAGE(3, 0);
  STAGE(0, 1); STAGE(1, 1); STAGE(2, 1);
  VMC6();
  BARX();

  for (int T = 0; T < NT; ++T) {
    const int ab = (((T & 1) << 2) + 2 + wm) << 13;
    const int bb = (((T & 1) << 2) + (wn >> 1)) << 13;
    // phase 1
    LDA(0, ab);
    LDB(bb);
    if (T + 1 < NT) STAGE(3, T + 1);
    BARX(); LGKM0();
    __builtin_amdgcn_s_setprio(1); QUAD(0, 0); __builtin_amdgcn_s_setprio(0);
    BARX();
    // phase 2
    if (T + 2 < NT) STAGE(0, T + 2);
    BARX();
    __builtin_amdgcn_s_setprio(1); QUAD(0, 1); __builtin_amdgcn_s_setprio(0);
    BARX();
    // phase 3
    LDA(1, ab);
    if (T + 2 < NT) STAGE(1, T + 2);
    BARX(); LGKM0();
    __builtin_amdgcn_s_setprio(1); QUAD(1, 0); __builtin_amdgcn_s_setprio(0);
    BARX();
    // phase 4
    if (T + 2 < NT) STAGE(2, T + 2);
    BARX();
    __builtin_amdgcn_s_setprio(1); QUAD(1, 1); __builtin_amdgcn_s_setprio(0);
    if (T < NT - 2) { VMC6(); } else { VMC0(); }
    BARX();
  }

  const int col = lane & 15;
  const int r4  = (lane >> 4) << 2;
#pragma unroll
  for (int nt = 0; nt < 4; ++nt) {
    const int gc = n0 + wn * 64 + nt * 16 + col;
    const float bias = b_enc[gc];
#pragma unroll
    for (int mt = 0; mt < 8; ++mt) {
#pragma unroll
      for (int r = 0; r < 4; ++r) {
        const int gr = m0 + wm * 128 + mt * 16 + r4 + r;
        a1[(size_t)gr * N_DIM + gc] = acc[mt][nt][r] + bias;
      }
    }
  }
#undef STAGE
#undef LDA
#undef LDB
#undef QUAD
}

// ---------------- top-96 per row on fp16-approx acts: bitwise radix select -------
#define TK_THREADS 512
#define TK_PER 64   // 32768 / 512
__launch_bounds__(512)
__global__ void topk_kernel(const float* __restrict__ a1, int* __restrict__ cand)
{
  const int row = blockIdx.x;
  const float* pr = a1 + (size_t)row * N_DIM;
  const int tid = threadIdx.x;

  unsigned u[TK_PER];
#pragma unroll
  for (int i = 0; i < TK_PER; ++i) {
    union { float f; unsigned b; } c;
    c.f = pr[i * TK_THREADS + tid];
    u[i] = (c.b & 0x80000000u) ? ~c.b : (c.b | 0x80000000u);  // order-preserving key
  }

  __shared__ int red[8];
  unsigned prefix = 0;
  int needed = NCAND;
  for (int bit = 31; bit >= 0; --bit) {
    unsigned want = (prefix >> bit) | 1u;
    int cnt = 0;
#pragma unroll
    for (int i = 0; i < TK_PER; ++i) cnt += ((u[i] >> bit) == want) ? 1 : 0;
    for (int off = 32; off > 0; off >>= 1) cnt += __shfl_down(cnt, off);
    if ((tid & 63) == 0) red[tid >> 6] = cnt;
    __syncthreads();
    int total = red[0] + red[1] + red[2] + red[3] + red[4] + red[5] + red[6] + red[7];
    __syncthreads();
    if (total >= needed) prefix |= (1u << bit);
    else needed -= total;
  }
  __shared__ int c_gt, c_tie;
  if (tid == 0) { c_gt = 0; c_tie = 0; }
  __syncthreads();
#pragma unroll
  for (int i = 0; i < TK_PER; ++i) {
    if (u[i] > prefix) {
      int p = atomicAdd(&c_gt, 1);
      cand[row * NCAND + p] = i * TK_THREADS + tid;
    }
  }
  __syncthreads();
  int base = c_gt;
#pragma unroll
  for (int i = 0; i < TK_PER; ++i) {
    if (u[i] == prefix) {
      int t = atomicAdd(&c_tie, 1);
      if (t < needed) cand[row * NCAND + base + t] = i * TK_THREADS + tid;
    }
  }
}

// ---------------- mark: classify candidates as certain-in / certain-out / ambiguous
// in:  >=32 candidates certainly below (approx diff > 2*delta)  -> exact rank < 64
// out: >=64 candidates certainly above                          -> exact rank >= 64
// else ambiguous -> needs exact fp32 value. Certain-ins keep approx vals (output
// error contribution <= ~3e-4, dominated by fp16 decode weights).
__launch_bounds__(128)
__global__ void mark_kernel(const float* __restrict__ a1, const int* __restrict__ cand,
                            int* __restrict__ nIn, int* __restrict__ nAmb,
                            int* __restrict__ ambIdx,
                            int* __restrict__ tk_idx, float* __restrict__ tk_val)
{
  const int row = blockIdx.x, tid = threadIdx.x;
  __shared__ float sv[NCAND];
  __shared__ int   si[NCAND];
  __shared__ int cin, camb;
  if (tid == 0) { cin = 0; camb = 0; }
  if (tid < NCAND) {
    int cj = cand[row * NCAND + tid];
    si[tid] = cj;
    sv[tid] = a1[(size_t)row * N_DIM + cj];
  }
  __syncthreads();
  if (tid < NCAND) {
    float v = sv[tid];
    int above = 0, below = 0;
    for (int j = 0; j < NCAND; ++j) {
      above += (sv[j] > v + MARGIN2) ? 1 : 0;
      below += (sv[j] < v - MARGIN2) ? 1 : 0;
    }
    if (below >= NCAND - TOPK) {          // certainly in exact top-64
      int p = atomicAdd(&cin, 1);
      tk_idx[row * TOPK + p] = si[tid];
      tk_val[row * TOPK + p] = v;
    } else if (above < TOPK) {            // not certainly out -> ambiguous
      int q = atomicAdd(&camb, 1);
      ambIdx[row * NCAND + q] = si[tid];
    }
  }
  __syncthreads();
  if (tid == 0) { nIn[row] = cin; nAmb[row] = camb; }
}

// ---------------- refine+select: exact fp32 dots for ambiguous only, fill slots --
// dot-product op sequence textually identical to the previously-passing refine
// (per-lane float4 MACs + shfl_down tree + bias add) -> deterministic exact vals.
__launch_bounds__(256)
__global__ void refine_select(const float* __restrict__ x, const float* __restrict__ W,
                              const float* __restrict__ b_enc,
                              const int* __restrict__ nIn, const int* __restrict__ nAmb,
                              const int* __restrict__ ambIdx,
                              int* __restrict__ tk_idx, float* __restrict__ tk_val)
{
  const int row = blockIdx.x;
  const int na = nAmb[row];
  if (na == 0) return;
  const int ni = nIn[row];
  const int need = TOPK - ni;
  const int tid = threadIdx.x, lane = tid & 63, wave = tid >> 6;
  __shared__ float ev[NCAND];
  __shared__ int   ei[NCAND];
  __shared__ int spos;
  if (tid == 0) spos = 0;

  const float* xr = x + (size_t)row * K_DIM;
  float4 xv[16];
#pragma unroll
  for (int c = 0; c < 16; ++c) xv[c] = *(const float4*)(xr + c * 256 + lane * 4);

  for (int e = wave; e < na; e += 4) {
    int cj = ambIdx[row * NCAND + e];
    const float* wr = W + (size_t)cj * K_DIM;
    float acc = 0.f;
#pragma unroll
    for (int c = 0; c < 16; ++c) {
      float4 wv = *(const float4*)(wr + c * 256 + lane * 4);
      acc += xv[c].x * wv.x + xv[c].y * wv.y + xv[c].z * wv.z + xv[c].w * wv.w;
    }
#pragma unroll
    for (int off = 32; off > 0; off >>= 1) acc += __shfl_down(acc, off, 64);
    if (lane == 0) { ev[e] = acc + b_enc[cj]; ei[e] = cj; }
  }
  __syncthreads();

  if (tid < na && need > 0) {
    float v = ev[tid];
    int my = ei[tid];
    int rank = 0;
    for (int i = 0; i < na; ++i) {
      float vi = ev[i];
      rank += (vi > v || (vi == v && ei[i] < my)) ? 1 : 0;  // lax.top_k tie-break
    }
    if (rank < need) {
      int p = atomicAdd(&spos, 1);
      tk_idx[row * TOPK + ni + p] = my;
      tk_val[row * TOPK + ni + p] = v;
    }
  }
}

// ---------------- sparse tied-weight decode: z2 = sum val_j * W[idx_j,:] + b_dec --
__launch_bounds__(256)
__global__ void decode_kernel(const _Float16* __restrict__ wh, const int* __restrict__ tk_idx,
                              const float* __restrict__ tk_val, const float* __restrict__ b_dec,
                              float* __restrict__ out)
{
  const int row = blockIdx.x, tid = threadIdx.x;
  __shared__ int   sidx[TOPK];
  __shared__ float sval[TOPK];
  if (tid < TOPK) { sidx[tid] = tk_idx[row * TOPK + tid]; sval[tid] = tk_val[row * TOPK + tid]; }
  __syncthreads();

  const int c0 = tid * 8;
  const int c1 = (tid + 256) * 8;
  float acc0[8], acc1[8];
#pragma unroll
  for (int e = 0; e < 8; ++e) { acc0[e] = b_dec[c0 + e]; acc1[e] = b_dec[c1 + e]; }

  for (int j = 0; j < TOPK; ++j) {
    const _Float16* wr = wh + (size_t)sidx[j] * K_DIM;
    half8 w0 = *(const half8*)(wr + c0);
    half8 w1 = *(const half8*)(wr + c1);
    float v = sval[j];
#pragma unroll
    for (int e = 0; e < 8; ++e) { acc0[e] += v * (float)w0[e]; acc1[e] += v * (float)w1[e]; }
  }
  float* po = out + (size_t)row * K_DIM;
#pragma unroll
  for (int e = 0; e < 8; ++e) { po[c0 + e] = acc0[e]; po[c1 + e] = acc1[e]; }
}

extern "C" void kernel_launch(void* const* d_in, const int* in_sizes, int n_in,
                              void* d_out, int out_size, void* d_ws, size_t ws_size,
                              hipStream_t stream) {
  const float* x     = (const float*)d_in[0];
  const float* W     = (const float*)d_in[1];
  const float* b_enc = (const float*)d_in[2];
  const float* b_dec = (const float*)d_in[3];

  // workspace carve (same footprint as previous passing rounds)
  _Float16* x_h = (_Float16*)d_ws;
  _Float16* w_h = x_h + (size_t)M_DIM * K_DIM;
  float*    a1  = (float*)(w_h + (size_t)N_DIM * K_DIM);
  int*      cand = (int*)(a1 + (size_t)M_DIM * N_DIM);
  int*      tk_idx = cand + (size_t)M_DIM * NCAND;
  float*    tk_val = (float*)(tk_idx + M_DIM * TOPK);

  // mark/refine scratch aliases x_h (dead after gemm_enc; a1 must stay intact
  // through mark_kernel's gathered reads, so it cannot be aliased)
  int* nIn    = (int*)x_h;
  int* nAmb   = nIn + M_DIM;
  int* ambIdx = nAmb + M_DIM;

  cast_kernel<<<4096, 256, 0, stream>>>((const float4*)x, (half4*)x_h,
                                        (int)((size_t)M_DIM * K_DIM / 4));
  cast_kernel<<<8192, 256, 0, stream>>>((const float4*)W, (half4*)w_h,
                                        (int)((size_t)N_DIM * K_DIM / 4));
  gemm_enc<<<(M_DIM / 256) * (N_DIM / 256), 512, 0, stream>>>(x_h, w_h, b_enc, a1);
  topk_kernel<<<M_DIM, TK_THREADS, 0, stream>>>(a1, cand);
  mark_kernel<<<M_DIM, 128, 0, stream>>>(a1, cand, nIn, nAmb, ambIdx, tk_idx, tk_val);
  refine_select<<<M_DIM, 256, 0, stream>>>(x, W, b_enc, nIn, nAmb, ambIdx, tk_idx, tk_val);
  decode_kernel<<<M_DIM, 256, 0, stream>>>(w_h, tk_idx, tk_val, b_dec, (float*)d_out);
}